// Round 11
// baseline (75.287 us; speedup 1.0000x reference)
//
#include <hip/hip_runtime.h>

#define NBLK 768
#define NTHR 256
#define H1_BINS 2048
#define H1_SHIFT 20
#define H2_BINS (1u << H1_SHIFT)      // 1048576
#define H2_MASK (H2_BINS - 1u)
#define CHUNK 2048
#define NCHUNK 512
#define UNROLL 4
#define TILE (NTHR * UNROLL)
#define STAGE_ELEMS 1024              // elements per stage (NTHR * 4)

// ws layout (bytes):
//   CTRL   [0,256): u64[0]=posCnt u64[1]=negCnt u64[2]=b1 u64[3]=need u64[4]=k
//                   dbl[5]=posLoss dbl[6]=totLoss dbl[7]=sumAbove dbl[8]=approxWithin
//                   u64[9]=mode (1=approx: skip pass2)
//   gcnt   [1024, 17408)     2048 x u64
//   gsum   [17408, 33792)    2048 x u64  (loss * 2^23 fixed point)
//   p1part [40960, 53248)    NBLK x 2 doubles
//   chunkCnt [57344, 61440)  512 x u64
//   chunkW   [61440, 65536)  512 x double
//   H2     [65536, 4259840)  2^20 x u32
#define OFF_CNT   1024
#define OFF_SUM   17408
#define OFF_P1    40960
#define OFF_CCNT  57344
#define OFF_CW    61440
#define OFF_H2    65536
#define MEMSET1   33792

#define LN2F 0.69314718055994531f
#define FIXSCALE 8388608.0f           // 2^23
#define INV_FIX  (1.0 / 8388608.0)
#define CNT_SHIFT 46
#define SUM_MASK ((1ULL << CNT_SHIFT) - 1ULL)
#define APPROX_GATE 3e-3

#define WAIT_VM3()   asm volatile("s_waitcnt vmcnt(3)" ::: "memory")
#define WAIT_VM0()   asm volatile("s_waitcnt vmcnt(0)" ::: "memory")
#define WAIT_LGKM0() asm volatile("s_waitcnt lgkmcnt(0)" ::: "memory")

__device__ __forceinline__ void elem_compute(float pp, int tt, float mm,
                                             float& loss, bool& pos, bool& neg) {
    bool isz = (tt == 0);
    float x = isz ? pp : (1.0f - pp);
    float lr = fminf(-__log2f(x) * LN2F, 100.0f);   // >= 0; log2(0) -> 100
    loss = lr * mm;
    float tm = isz ? mm : 0.0f;
    pos = (tm == 1.0f);
    neg = (tm == 0.0f);
}

__device__ __forceinline__ void stage16(const void* g, void* l) {
    __builtin_amdgcn_global_load_lds(
        (const __attribute__((address_space(1))) unsigned int*)g,
        (__attribute__((address_space(3))) unsigned int*)l,
        16, 0, 0);
}

__global__ __launch_bounds__(NTHR) void pass1(const float* __restrict__ pred,
                                              const int* __restrict__ targ,
                                              const float* __restrict__ mask,
                                              int n,
                                              unsigned long long* __restrict__ gcnt,
                                              unsigned long long* __restrict__ gsum,
                                              unsigned long long* __restrict__ ctrl,
                                              double* __restrict__ p1part) {
    __shared__ unsigned char sbufP[2][4096];
    __shared__ unsigned char sbufT[2][4096];
    __shared__ unsigned char sbufM[2][4096];
    __shared__ unsigned long long spack[H1_BINS];   // 16 KB: cnt<<46 | fixsum
    __shared__ double sredd[NTHR];
    __shared__ unsigned sredu[NTHR];
    int tid = threadIdx.x;
    int w = tid >> 6;            // wave id (4 waves)
    int wbase = w << 10;         // wave-uniform 1 KB segment base
    for (int i = tid; i < H1_BINS; i += NTHR) spack[i] = 0ULL;
    __syncthreads();

    float posLoss = 0.f, totLoss = 0.f;
    unsigned posCnt = 0, negCnt = 0;

    int totStages = n >> 10;     // full 1024-elem stages
    int perblk = (totStages + NBLK - 1) / NBLK;
    int sBeg = blockIdx.x * perblk;
    int sEnd = sBeg + perblk; if (sEnd > totStages) sEnd = totStages;

    if (sBeg < sEnd) {
        // prologue: issue stage sBeg into buf 0
        {
            int e = (sBeg << 10) + tid * 4;
            stage16(pred + e, &sbufP[0][wbase]);
            stage16(targ + e, &sbufT[0][wbase]);
            stage16(mask + e, &sbufM[0][wbase]);
        }
        int b = 0;
        for (int s = sBeg; s < sEnd; ++s) {
            bool more = (s + 1 < sEnd);
            if (more) {
                int e = ((s + 1) << 10) + tid * 4;
                stage16(pred + e, &sbufP[b ^ 1][wbase]);
                stage16(targ + e, &sbufT[b ^ 1][wbase]);
                stage16(mask + e, &sbufM[b ^ 1][wbase]);
                WAIT_VM3();      // stage s's 3 loads complete; 3 newer in flight
            } else {
                WAIT_VM0();
            }
            float4 p = *(const float4*)&sbufP[b][tid * 16];
            int4   t = *(const int4*)  &sbufT[b][tid * 16];
            float4 m = *(const float4*)&sbufM[b][tid * 16];
            WAIT_LGKM0();        // reads done before buf b is restaged next iter
            float pa[4] = {p.x, p.y, p.z, p.w};
            int   ta[4] = {t.x, t.y, t.z, t.w};
            float ma[4] = {m.x, m.y, m.z, m.w};
            #pragma unroll
            for (int j = 0; j < 4; ++j) {
                float loss; bool pos, neg;
                elem_compute(pa[j], ta[j], ma[j], loss, pos, neg);
                totLoss += loss;
                if (pos) { posCnt++; posLoss += loss; }
                if (neg) {
                    negCnt++;
                    unsigned u = __float_as_uint(loss);
                    if (u & 0x80000000u) u = 0u;
                    unsigned long long pk = (1ULL << CNT_SHIFT) |
                                            (unsigned long long)(loss * FIXSCALE);
                    atomicAdd(&spack[u >> H1_SHIFT], pk);
                }
            }
            b ^= 1;
        }
    }
    // scalar tail: [totStages*1024, n)
    for (int i = (totStages << 10) + blockIdx.x * blockDim.x + tid; i < n;
         i += gridDim.x * blockDim.x) {
        float loss; bool pos, neg;
        elem_compute(pred[i], targ[i], mask[i], loss, pos, neg);
        totLoss += loss;
        if (pos) { posCnt++; posLoss += loss; }
        if (neg) {
            negCnt++;
            unsigned u = __float_as_uint(loss);
            if (u & 0x80000000u) u = 0u;
            unsigned long long pk = (1ULL << CNT_SHIFT) |
                                    (unsigned long long)(loss * FIXSCALE);
            atomicAdd(&spack[u >> H1_SHIFT], pk);
        }
    }
    __syncthreads();
    for (int bidx = tid; bidx < H1_BINS; bidx += NTHR) {
        unsigned long long pk = spack[bidx];
        if (pk) {
            atomicAdd(&gcnt[bidx], pk >> CNT_SHIFT);
            atomicAdd(&gsum[bidx], pk & SUM_MASK);
        }
    }
    sredd[tid] = (double)posLoss; __syncthreads();
    for (int s = NTHR / 2; s > 0; s >>= 1) { if (tid < s) sredd[tid] += sredd[tid + s]; __syncthreads(); }
    if (tid == 0) p1part[2 * blockIdx.x] = sredd[0];
    __syncthreads();
    sredd[tid] = (double)totLoss; __syncthreads();
    for (int s = NTHR / 2; s > 0; s >>= 1) { if (tid < s) sredd[tid] += sredd[tid + s]; __syncthreads(); }
    if (tid == 0) p1part[2 * blockIdx.x + 1] = sredd[0];
    __syncthreads();
    sredu[tid] = posCnt; __syncthreads();
    for (int s = NTHR / 2; s > 0; s >>= 1) { if (tid < s) sredu[tid] += sredu[tid + s]; __syncthreads(); }
    if (tid == 0) atomicAdd(&ctrl[0], (unsigned long long)sredu[0]);
    __syncthreads();
    sredu[tid] = negCnt; __syncthreads();
    for (int s = NTHR / 2; s > 0; s >>= 1) { if (tid < s) sredu[tid] += sredu[tid + s]; __syncthreads(); }
    if (tid == 0) atomicAdd(&ctrl[1], (unsigned long long)sredu[0]);
}

__global__ __launch_bounds__(1024) void findbin(const unsigned long long* __restrict__ gcnt,
                                                const unsigned long long* __restrict__ gsum,
                                                unsigned long long* __restrict__ ctrl,
                                                const double* __restrict__ p1part) {
    __shared__ double sd[1024];
    __shared__ unsigned long long ssA[1024];
    __shared__ unsigned long long ssB[1024];
    int tid = threadIdx.x;
    sd[tid] = (tid < NBLK) ? p1part[2 * tid] : 0.0; __syncthreads();
    for (int s = 512; s > 0; s >>= 1) { if (tid < s) sd[tid] += sd[tid + s]; __syncthreads(); }
    double posLoss = sd[0]; __syncthreads();
    sd[tid] = (tid < NBLK) ? p1part[2 * tid + 1] : 0.0; __syncthreads();
    for (int s = 512; s > 0; s >>= 1) { if (tid < s) sd[tid] += sd[tid + s]; __syncthreads(); }
    double totLoss = sd[0]; __syncthreads();

    unsigned long long posCnt = ctrl[0];
    unsigned long long negCnt = ctrl[1];
    unsigned long long k = posCnt * 5ULL;
    if (k > negCnt) k = negCnt;

    int base = tid * 2;
    unsigned long long h0 = gcnt[base], h1 = gcnt[base + 1];
    unsigned long long f0 = gsum[base], f1 = gsum[base + 1];
    ssA[tid] = h0 + h1; ssB[tid] = f0 + f1; __syncthreads();
    for (int d = 1; d < 1024; d <<= 1) {
        unsigned long long a = (tid + d < 1024) ? ssA[tid + d] : 0ULL;
        unsigned long long b = (tid + d < 1024) ? ssB[tid + d] : 0ULL;
        __syncthreads();
        ssA[tid] += a; ssB[tid] += b;
        __syncthreads();
    }
    unsigned long long run  = (tid == 1023) ? 0ULL : ssA[tid + 1];
    unsigned long long frun = (tid == 1023) ? 0ULL : ssB[tid + 1];

    if (k > 0) {
        unsigned long long hh[2] = {h1, h0};
        unsigned long long ff[2] = {f1, f0};
        int off[2] = {1, 0};
        #pragma unroll
        for (int j = 0; j < 2; ++j) {
            unsigned long long c = hh[j];
            if (run < k && k <= run + c) {
                unsigned b1 = (unsigned)(base + off[j]);
                unsigned long long need = k - run;
                double sumAbove = (double)frun * INV_FIX;
                double avg = ((double)ff[j] / (double)c) * INV_FIX;
                double approxWithin = (double)need * avg;
                int e = (int)((b1 >> 3) & 0xFF);
                double width = ldexp(1.0, (e > 0 ? e : 1) - 130);
                double denom = (double)posCnt + (double)k + 1e-8;
                double errBound = (double)need * width / denom;
                ctrl[2] = (unsigned long long)b1;
                ctrl[3] = need;
                ((double*)ctrl)[7] = sumAbove;
                ((double*)ctrl)[8] = approxWithin;
                ctrl[9] = (errBound <= APPROX_GATE) ? 1ULL : 0ULL;
            }
            run += c; frun += ff[j];
        }
    } else if (tid == 0) {
        ctrl[2] = (unsigned long long)H1_BINS;
        ctrl[3] = 0;
        ((double*)ctrl)[7] = 0.0;
        ((double*)ctrl)[8] = 0.0;
        ctrl[9] = 1ULL;
    }
    if (tid == 0) {
        ctrl[4] = k;
        ((double*)ctrl)[5] = posLoss;
        ((double*)ctrl)[6] = totLoss;
    }
}

// exact-mode only: sub-histogram of bin b1 (early-out when mode==approx)
__global__ __launch_bounds__(NTHR) void pass2x(const float* __restrict__ pred,
                                               const int* __restrict__ targ,
                                               const float* __restrict__ mask,
                                               int n,
                                               const unsigned long long* __restrict__ ctrl,
                                               unsigned* __restrict__ gH2) {
    if (ctrl[9] == 1ULL) return;
    unsigned b1 = (unsigned)ctrl[2];
    int tid = threadIdx.x;
    int nv = n >> 2;
    const float4* p4 = (const float4*)pred;
    const int4*   t4 = (const int4*)targ;
    const float4* m4 = (const float4*)mask;

    int tiles = (nv + TILE - 1) / TILE;
    int perblk = (tiles + NBLK - 1) / NBLK;
    int tstart = blockIdx.x * perblk;
    int tend = tstart + perblk; if (tend > tiles) tend = tiles;

    for (int tt = tstart; tt < tend; ++tt) {
        int g = tt * TILE + tid;
        bool full = (tt * TILE + TILE) <= nv;
        float4 p[UNROLL]; int4 t[UNROLL]; float4 m[UNROLL];
        bool ok[UNROLL];
        if (full) {
            #pragma unroll
            for (int k = 0; k < UNROLL; ++k) {
                p[k] = p4[g + k * NTHR]; t[k] = t4[g + k * NTHR]; m[k] = m4[g + k * NTHR];
                ok[k] = true;
            }
        } else {
            #pragma unroll
            for (int k = 0; k < UNROLL; ++k) {
                ok[k] = (g + k * NTHR) < nv;
                if (ok[k]) { p[k] = p4[g + k * NTHR]; t[k] = t4[g + k * NTHR]; m[k] = m4[g + k * NTHR]; }
            }
        }
        #pragma unroll
        for (int k = 0; k < UNROLL; ++k) {
            if (!ok[k]) continue;
            float pa[4] = {p[k].x, p[k].y, p[k].z, p[k].w};
            int   ta[4] = {t[k].x, t[k].y, t[k].z, t[k].w};
            float ma[4] = {m[k].x, m[k].y, m[k].z, m[k].w};
            #pragma unroll
            for (int j = 0; j < 4; ++j) {
                float loss; bool pos, neg;
                elem_compute(pa[j], ta[j], ma[j], loss, pos, neg);
                if (neg) {
                    unsigned u = __float_as_uint(loss);
                    if (u & 0x80000000u) u = 0u;
                    if ((u >> H1_SHIFT) == b1) atomicAdd(&gH2[u & H2_MASK], 1u);
                }
            }
        }
    }
    for (int i = (nv << 2) + blockIdx.x * blockDim.x + tid; i < n; i += gridDim.x * blockDim.x) {
        float loss; bool pos, neg;
        elem_compute(pred[i], targ[i], mask[i], loss, pos, neg);
        if (neg) {
            unsigned u = __float_as_uint(loss);
            if (u & 0x80000000u) u = 0u;
            if ((u >> H1_SHIFT) == b1) atomicAdd(&gH2[u & H2_MASK], 1u);
        }
    }
}

__global__ __launch_bounds__(256) void chunkscan(const unsigned* __restrict__ gH2,
                                                 const unsigned long long* __restrict__ ctrl,
                                                 unsigned long long* __restrict__ chunkCnt,
                                                 double* __restrict__ chunkW) {
    __shared__ unsigned long long sc[256];
    __shared__ double sw[256];
    int tid = threadIdx.x;
    unsigned b1 = (unsigned)ctrl[2];
    bool active = (ctrl[9] == 0ULL) && (b1 < H1_BINS);
    int base = blockIdx.x * CHUNK;
    unsigned long long cnt = 0; double w = 0.0;
    if (active) {
        for (int i = tid; i < CHUNK; i += 256) {
            unsigned c = gH2[base + i];
            if (c) {
                float L = __uint_as_float((b1 << H1_SHIFT) | (unsigned)(base + i));
                cnt += c;
                w += (double)c * (double)L;
            }
        }
    }
    sc[tid] = cnt; sw[tid] = w; __syncthreads();
    for (int s = 128; s > 0; s >>= 1) {
        if (tid < s) { sc[tid] += sc[tid + s]; sw[tid] += sw[tid + s]; }
        __syncthreads();
    }
    if (tid == 0) { chunkCnt[blockIdx.x] = sc[0]; chunkW[blockIdx.x] = sw[0]; }
}

__global__ __launch_bounds__(512) void finalize(const unsigned* __restrict__ gH2,
                                                const unsigned long long* __restrict__ ctrl,
                                                const unsigned long long* __restrict__ chunkCnt,
                                                const double* __restrict__ chunkW,
                                                float* __restrict__ out, int n) {
    __shared__ unsigned long long sc[512];
    __shared__ double sw[512];
    __shared__ int s_cstar;
    __shared__ unsigned long long s_rem;
    __shared__ double s_wAbove;
    __shared__ double s_res;
    int tid = threadIdx.x;

    unsigned long long posCnt = ctrl[0];
    unsigned long long b1 = ctrl[2];
    unsigned long long need = ctrl[3];
    unsigned long long k = ctrl[4];
    double posLoss = ((const double*)ctrl)[5];
    double totLoss = ((const double*)ctrl)[6];
    double sumAbove = ((const double*)ctrl)[7];
    double approxWithin = ((const double*)ctrl)[8];
    unsigned long long mode = ctrl[9];

    double within = approxWithin;

    if (mode == 0ULL && need > 0) {
        if (tid == 0) { s_cstar = 0; s_rem = 1; s_wAbove = 0.0; s_res = 0.0; }
        unsigned long long myc = chunkCnt[tid];
        double myw = chunkW[tid];
        sc[tid] = myc; sw[tid] = myw; __syncthreads();
        for (int d = 1; d < 512; d <<= 1) {
            unsigned long long ac = (tid + d < 512) ? sc[tid + d] : 0ULL;
            double aw = (tid + d < 512) ? sw[tid + d] : 0.0;
            __syncthreads();
            sc[tid] += ac; sw[tid] += aw;
            __syncthreads();
        }
        unsigned long long afterC = (tid == 511) ? 0ULL : sc[tid + 1];
        double afterW = (tid == 511) ? 0.0 : sw[tid + 1];
        if (afterC < need && need <= afterC + myc) {
            s_cstar = tid; s_rem = need - afterC; s_wAbove = afterW;
        }
        __syncthreads();
        int cstar = s_cstar;
        unsigned long long rem = s_rem;
        double wAbove = s_wAbove;
        __syncthreads();

        int pb = cstar * CHUNK + 4 * tid;
        unsigned c[4]; double L[4];
        unsigned long long tot = 0; double wtot = 0.0;
        #pragma unroll
        for (int j = 0; j < 4; ++j) {
            c[j] = gH2[pb + j];
            L[j] = (double)__uint_as_float(((unsigned)b1 << H1_SHIFT) | (unsigned)(pb + j));
            tot += c[j];
            wtot += (double)c[j] * L[j];
        }
        sc[tid] = tot; sw[tid] = wtot;
        __syncthreads();
        for (int d = 1; d < 512; d <<= 1) {
            unsigned long long ac = (tid + d < 512) ? sc[tid + d] : 0ULL;
            double aw = (tid + d < 512) ? sw[tid + d] : 0.0;
            __syncthreads();
            sc[tid] += ac; sw[tid] += aw;
            __syncthreads();
        }
        unsigned long long run = (tid == 511) ? 0ULL : sc[tid + 1];
        double wrun = (tid == 511) ? 0.0 : sw[tid + 1];
        #pragma unroll
        for (int j = 3; j >= 0; --j) {
            if (run < rem && rem <= run + c[j]) {
                s_res = wrun + (double)(rem - run) * L[j];
            }
            run += c[j];
            wrun += (double)c[j] * L[j];
        }
        __syncthreads();
        within = wAbove + s_res;
    }

    if (tid == 0) {
        double negLoss = sumAbove + within;
        double result;
        if (posCnt == 0) {
            result = totLoss / (double)n;
        } else {
            result = (posLoss + negLoss) / ((double)posCnt + (double)k + 1e-8);
        }
        out[0] = (float)result;
    }
}

extern "C" void kernel_launch(void* const* d_in, const int* in_sizes, int n_in,
                              void* d_out, int out_size, void* d_ws, size_t ws_size,
                              hipStream_t stream) {
    const float* pred = (const float*)d_in[0];
    const int*   targ = (const int*)d_in[1];
    const float* mask = (const float*)d_in[2];
    int n = in_sizes[0];

    char* ws = (char*)d_ws;
    unsigned long long* ctrl = (unsigned long long*)ws;
    unsigned long long* gcnt = (unsigned long long*)(ws + OFF_CNT);
    unsigned long long* gsum = (unsigned long long*)(ws + OFF_SUM);
    double* p1part = (double*)(ws + OFF_P1);
    unsigned long long* chunkCnt = (unsigned long long*)(ws + OFF_CCNT);
    double* chunkW = (double*)(ws + OFF_CW);
    unsigned* gH2 = (unsigned*)(ws + OFF_H2);

    (void)hipMemsetAsync(ws, 0, MEMSET1, stream);                 // ctrl + gcnt + gsum
    (void)hipMemsetAsync(ws + OFF_H2, 0, H2_BINS * 4, stream);    // H2

    pass1<<<NBLK, NTHR, 0, stream>>>(pred, targ, mask, n, gcnt, gsum, ctrl, p1part);
    findbin<<<1, 1024, 0, stream>>>(gcnt, gsum, ctrl, p1part);
    pass2x<<<NBLK, NTHR, 0, stream>>>(pred, targ, mask, n, ctrl, gH2);
    chunkscan<<<NCHUNK, 256, 0, stream>>>(gH2, ctrl, chunkCnt, chunkW);
    finalize<<<1, 512, 0, stream>>>(gH2, ctrl, chunkCnt, chunkW, (float*)d_out, n);
}

// Round 12
// 71.842 us; speedup vs baseline: 1.0480x; 1.0480x over previous
//
#include <hip/hip_runtime.h>

#define NBLK 1024
#define NTHR 256
#define H1_BINS 2048
#define H1_SHIFT 20
#define H2_BINS (1u << H1_SHIFT)      // 1048576
#define H2_MASK (H2_BINS - 1u)
#define CHUNK 2048
#define NCHUNK 512
#define UNROLL 4
#define TILE (NTHR * UNROLL)

// ws layout (bytes):
//   CTRL   [0,256): u64[0]=posCnt u64[1]=negCnt u64[2]=b1 u64[3]=need u64[4]=k
//                   dbl[5]=posLoss dbl[6]=totLoss dbl[7]=sumAbove dbl[8]=approxWithin
//                   u64[9]=mode (1=approx: skip pass2)
//   gcnt   [1024, 17408)     2048 x u64
//   gsum   [17408, 33792)    2048 x u64  (loss * 2^23 fixed point)
//   p1part [40960, 57344)    NBLK x 2 doubles
//   chunkCnt [57344, 61440)  512 x u64
//   chunkW   [61440, 65536)  512 x double
//   H2     [65536, 4259840)  2^20 x u32
#define OFF_CNT   1024
#define OFF_SUM   17408
#define OFF_P1    40960
#define OFF_CCNT  57344
#define OFF_CW    61440
#define OFF_H2    65536
#define MEMSET1   33792

#define LN2F 0.69314718055994531f
#define FIXSCALE 8388608.0f           // 2^23
#define INV_FIX  (1.0 / 8388608.0)
#define CNT_SHIFT 44
#define SUM_MASK ((1ULL << CNT_SHIFT) - 1ULL)
#define APPROX_GATE 3e-3

__device__ __forceinline__ void elem_compute(float pp, int tt, float mm,
                                             float& loss, bool& pos, bool& neg) {
    bool isz = (tt == 0);
    float x = isz ? pp : (1.0f - pp);
    float lr = fminf(-__log2f(x) * LN2F, 100.0f);   // >= 0; log2(0) -> 100
    loss = lr * mm;
    float tm = isz ? mm : 0.0f;
    pos = (tm == 1.0f);
    neg = (tm == 0.0f);
}

__global__ __launch_bounds__(NTHR) void pass1(const float* __restrict__ pred,
                                              const int* __restrict__ targ,
                                              const float* __restrict__ mask,
                                              int n,
                                              unsigned long long* __restrict__ gcnt,
                                              unsigned long long* __restrict__ gsum,
                                              unsigned long long* __restrict__ ctrl,
                                              double* __restrict__ p1part) {
    __shared__ unsigned long long spack[H1_BINS];   // 16 KB: cnt<<44 | fixsum
    __shared__ double sredd[NTHR];
    __shared__ unsigned sredu[NTHR];
    int tid = threadIdx.x;
    for (int i = tid; i < H1_BINS; i += NTHR) spack[i] = 0ULL;
    __syncthreads();

    float posLoss = 0.f, totLoss = 0.f;
    unsigned posCnt = 0, negCnt = 0;

    int nv = n >> 2;
    const float4* p4 = (const float4*)pred;
    const int4*   t4 = (const int4*)targ;
    const float4* m4 = (const float4*)mask;

    int tiles = (nv + TILE - 1) / TILE;
    int perblk = (tiles + NBLK - 1) / NBLK;
    int tstart = blockIdx.x * perblk;
    int tend = tstart + perblk; if (tend > tiles) tend = tiles;

    for (int tt = tstart; tt < tend; ++tt) {
        int g = tt * TILE + tid;
        bool full = (tt * TILE + TILE) <= nv;
        float4 p[UNROLL]; int4 t[UNROLL]; float4 m[UNROLL];
        bool ok[UNROLL];
        if (full) {
            #pragma unroll
            for (int k = 0; k < UNROLL; ++k) {
                p[k] = p4[g + k * NTHR]; t[k] = t4[g + k * NTHR]; m[k] = m4[g + k * NTHR];
                ok[k] = true;
            }
        } else {
            #pragma unroll
            for (int k = 0; k < UNROLL; ++k) {
                ok[k] = (g + k * NTHR) < nv;
                if (ok[k]) { p[k] = p4[g + k * NTHR]; t[k] = t4[g + k * NTHR]; m[k] = m4[g + k * NTHR]; }
            }
        }
        #pragma unroll
        for (int k = 0; k < UNROLL; ++k) {
            if (!ok[k]) continue;
            float pa[4] = {p[k].x, p[k].y, p[k].z, p[k].w};
            int   ta[4] = {t[k].x, t[k].y, t[k].z, t[k].w};
            float ma[4] = {m[k].x, m[k].y, m[k].z, m[k].w};
            #pragma unroll
            for (int j = 0; j < 4; ++j) {
                float loss; bool pos, neg;
                elem_compute(pa[j], ta[j], ma[j], loss, pos, neg);
                totLoss += loss;
                if (pos) { posCnt++; posLoss += loss; }
                if (neg) {
                    negCnt++;
                    unsigned u = __float_as_uint(loss);
                    if (u & 0x80000000u) u = 0u;     // -0 -> 0
                    unsigned long long pk = (1ULL << CNT_SHIFT) |
                                            (unsigned long long)(loss * FIXSCALE);
                    atomicAdd(&spack[u >> H1_SHIFT], pk);
                }
            }
        }
    }
    // scalar tail (n % 4)
    for (int i = (nv << 2) + blockIdx.x * blockDim.x + tid; i < n; i += gridDim.x * blockDim.x) {
        float loss; bool pos, neg;
        elem_compute(pred[i], targ[i], mask[i], loss, pos, neg);
        totLoss += loss;
        if (pos) { posCnt++; posLoss += loss; }
        if (neg) {
            negCnt++;
            unsigned u = __float_as_uint(loss);
            if (u & 0x80000000u) u = 0u;
            unsigned long long pk = (1ULL << CNT_SHIFT) |
                                    (unsigned long long)(loss * FIXSCALE);
            atomicAdd(&spack[u >> H1_SHIFT], pk);
        }
    }
    __syncthreads();
    // merge packed LDS hist -> global cnt/sum (skip empty bins)
    for (int b = tid; b < H1_BINS; b += NTHR) {
        unsigned long long pk = spack[b];
        if (pk) {
            atomicAdd(&gcnt[b], pk >> CNT_SHIFT);
            atomicAdd(&gsum[b], pk & SUM_MASK);
        }
    }
    // deterministic block reductions
    sredd[tid] = (double)posLoss; __syncthreads();
    for (int s = NTHR / 2; s > 0; s >>= 1) { if (tid < s) sredd[tid] += sredd[tid + s]; __syncthreads(); }
    if (tid == 0) p1part[2 * blockIdx.x] = sredd[0];
    __syncthreads();
    sredd[tid] = (double)totLoss; __syncthreads();
    for (int s = NTHR / 2; s > 0; s >>= 1) { if (tid < s) sredd[tid] += sredd[tid + s]; __syncthreads(); }
    if (tid == 0) p1part[2 * blockIdx.x + 1] = sredd[0];
    __syncthreads();
    sredu[tid] = posCnt; __syncthreads();
    for (int s = NTHR / 2; s > 0; s >>= 1) { if (tid < s) sredu[tid] += sredu[tid + s]; __syncthreads(); }
    if (tid == 0) atomicAdd(&ctrl[0], (unsigned long long)sredu[0]);
    __syncthreads();
    sredu[tid] = negCnt; __syncthreads();
    for (int s = NTHR / 2; s > 0; s >>= 1) { if (tid < s) sredu[tid] += sredu[tid + s]; __syncthreads(); }
    if (tid == 0) atomicAdd(&ctrl[1], (unsigned long long)sredu[0]);
}

__global__ __launch_bounds__(1024) void findbin(const unsigned long long* __restrict__ gcnt,
                                                const unsigned long long* __restrict__ gsum,
                                                unsigned long long* __restrict__ ctrl,
                                                const double* __restrict__ p1part) {
    __shared__ double sd[1024];
    __shared__ unsigned long long ssA[1024];   // count suffix
    __shared__ unsigned long long ssB[1024];   // fixsum suffix
    int tid = threadIdx.x;
    sd[tid] = p1part[2 * tid]; __syncthreads();
    for (int s = 512; s > 0; s >>= 1) { if (tid < s) sd[tid] += sd[tid + s]; __syncthreads(); }
    double posLoss = sd[0]; __syncthreads();
    sd[tid] = p1part[2 * tid + 1]; __syncthreads();
    for (int s = 512; s > 0; s >>= 1) { if (tid < s) sd[tid] += sd[tid + s]; __syncthreads(); }
    double totLoss = sd[0]; __syncthreads();

    unsigned long long posCnt = ctrl[0];
    unsigned long long negCnt = ctrl[1];
    unsigned long long k = posCnt * 5ULL;
    if (k > negCnt) k = negCnt;

    int base = tid * 2;
    unsigned long long h0 = gcnt[base], h1 = gcnt[base + 1];
    unsigned long long f0 = gsum[base], f1 = gsum[base + 1];
    ssA[tid] = h0 + h1; ssB[tid] = f0 + f1; __syncthreads();
    for (int d = 1; d < 1024; d <<= 1) {
        unsigned long long a = (tid + d < 1024) ? ssA[tid + d] : 0ULL;
        unsigned long long b = (tid + d < 1024) ? ssB[tid + d] : 0ULL;
        __syncthreads();
        ssA[tid] += a; ssB[tid] += b;
        __syncthreads();
    }
    unsigned long long run  = (tid == 1023) ? 0ULL : ssA[tid + 1];
    unsigned long long frun = (tid == 1023) ? 0ULL : ssB[tid + 1];

    if (k > 0) {
        unsigned long long hh[2] = {h1, h0};
        unsigned long long ff[2] = {f1, f0};
        int off[2] = {1, 0};
        #pragma unroll
        for (int j = 0; j < 2; ++j) {
            unsigned long long c = hh[j];
            if (run < k && k <= run + c) {
                unsigned b1 = (unsigned)(base + off[j]);
                unsigned long long need = k - run;
                double sumAbove = (double)frun * INV_FIX;
                double avg = ((double)ff[j] / (double)c) * INV_FIX;
                double approxWithin = (double)need * avg;
                // rigorous error bound: need * binwidth / denom
                int e = (int)((b1 >> 3) & 0xFF);
                double width = ldexp(1.0, (e > 0 ? e : 1) - 130);
                double denom = (double)posCnt + (double)k + 1e-8;
                double errBound = (double)need * width / denom;
                ctrl[2] = (unsigned long long)b1;
                ctrl[3] = need;
                ((double*)ctrl)[7] = sumAbove;
                ((double*)ctrl)[8] = approxWithin;
                ctrl[9] = (errBound <= APPROX_GATE) ? 1ULL : 0ULL;
            }
            run += c; frun += ff[j];
        }
    } else if (tid == 0) {
        ctrl[2] = (unsigned long long)H1_BINS;   // sentinel
        ctrl[3] = 0;
        ((double*)ctrl)[7] = 0.0;
        ((double*)ctrl)[8] = 0.0;
        ctrl[9] = 1ULL;                          // nothing to refine
    }
    if (tid == 0) {
        ctrl[4] = k;
        ((double*)ctrl)[5] = posLoss;
        ((double*)ctrl)[6] = totLoss;
    }
}

// exact-mode only: sub-histogram of bin b1 (early-out when mode==approx)
__global__ __launch_bounds__(NTHR) void pass2x(const float* __restrict__ pred,
                                               const int* __restrict__ targ,
                                               const float* __restrict__ mask,
                                               int n,
                                               const unsigned long long* __restrict__ ctrl,
                                               unsigned* __restrict__ gH2) {
    if (ctrl[9] == 1ULL) return;
    unsigned b1 = (unsigned)ctrl[2];
    int tid = threadIdx.x;
    int nv = n >> 2;
    const float4* p4 = (const float4*)pred;
    const int4*   t4 = (const int4*)targ;
    const float4* m4 = (const float4*)mask;

    int tiles = (nv + TILE - 1) / TILE;
    int perblk = (tiles + NBLK - 1) / NBLK;
    int tstart = blockIdx.x * perblk;
    int tend = tstart + perblk; if (tend > tiles) tend = tiles;

    for (int tt = tstart; tt < tend; ++tt) {
        int g = tt * TILE + tid;
        bool full = (tt * TILE + TILE) <= nv;
        float4 p[UNROLL]; int4 t[UNROLL]; float4 m[UNROLL];
        bool ok[UNROLL];
        if (full) {
            #pragma unroll
            for (int k = 0; k < UNROLL; ++k) {
                p[k] = p4[g + k * NTHR]; t[k] = t4[g + k * NTHR]; m[k] = m4[g + k * NTHR];
                ok[k] = true;
            }
        } else {
            #pragma unroll
            for (int k = 0; k < UNROLL; ++k) {
                ok[k] = (g + k * NTHR) < nv;
                if (ok[k]) { p[k] = p4[g + k * NTHR]; t[k] = t4[g + k * NTHR]; m[k] = m4[g + k * NTHR]; }
            }
        }
        #pragma unroll
        for (int k = 0; k < UNROLL; ++k) {
            if (!ok[k]) continue;
            float pa[4] = {p[k].x, p[k].y, p[k].z, p[k].w};
            int   ta[4] = {t[k].x, t[k].y, t[k].z, t[k].w};
            float ma[4] = {m[k].x, m[k].y, m[k].z, m[k].w};
            #pragma unroll
            for (int j = 0; j < 4; ++j) {
                float loss; bool pos, neg;
                elem_compute(pa[j], ta[j], ma[j], loss, pos, neg);
                if (neg) {
                    unsigned u = __float_as_uint(loss);
                    if (u & 0x80000000u) u = 0u;
                    if ((u >> H1_SHIFT) == b1) atomicAdd(&gH2[u & H2_MASK], 1u);
                }
            }
        }
    }
    for (int i = (nv << 2) + blockIdx.x * blockDim.x + tid; i < n; i += gridDim.x * blockDim.x) {
        float loss; bool pos, neg;
        elem_compute(pred[i], targ[i], mask[i], loss, pos, neg);
        if (neg) {
            unsigned u = __float_as_uint(loss);
            if (u & 0x80000000u) u = 0u;
            if ((u >> H1_SHIFT) == b1) atomicAdd(&gH2[u & H2_MASK], 1u);
        }
    }
}

__global__ __launch_bounds__(256) void chunkscan(const unsigned* __restrict__ gH2,
                                                 const unsigned long long* __restrict__ ctrl,
                                                 unsigned long long* __restrict__ chunkCnt,
                                                 double* __restrict__ chunkW) {
    __shared__ unsigned long long sc[256];
    __shared__ double sw[256];
    int tid = threadIdx.x;
    unsigned b1 = (unsigned)ctrl[2];
    bool active = (ctrl[9] == 0ULL) && (b1 < H1_BINS);
    int base = blockIdx.x * CHUNK;
    unsigned long long cnt = 0; double w = 0.0;
    if (active) {
        for (int i = tid; i < CHUNK; i += 256) {
            unsigned c = gH2[base + i];
            if (c) {
                float L = __uint_as_float((b1 << H1_SHIFT) | (unsigned)(base + i));
                cnt += c;
                w += (double)c * (double)L;
            }
        }
    }
    sc[tid] = cnt; sw[tid] = w; __syncthreads();
    for (int s = 128; s > 0; s >>= 1) {
        if (tid < s) { sc[tid] += sc[tid + s]; sw[tid] += sw[tid + s]; }
        __syncthreads();
    }
    if (tid == 0) { chunkCnt[blockIdx.x] = sc[0]; chunkW[blockIdx.x] = sw[0]; }
}

__global__ __launch_bounds__(512) void finalize(const unsigned* __restrict__ gH2,
                                                const unsigned long long* __restrict__ ctrl,
                                                const unsigned long long* __restrict__ chunkCnt,
                                                const double* __restrict__ chunkW,
                                                float* __restrict__ out, int n) {
    __shared__ unsigned long long sc[512];
    __shared__ double sw[512];
    __shared__ int s_cstar;
    __shared__ unsigned long long s_rem;
    __shared__ double s_wAbove;
    __shared__ double s_res;
    int tid = threadIdx.x;

    unsigned long long posCnt = ctrl[0];
    unsigned long long b1 = ctrl[2];
    unsigned long long need = ctrl[3];
    unsigned long long k = ctrl[4];
    double posLoss = ((const double*)ctrl)[5];
    double totLoss = ((const double*)ctrl)[6];
    double sumAbove = ((const double*)ctrl)[7];
    double approxWithin = ((const double*)ctrl)[8];
    unsigned long long mode = ctrl[9];

    double within = approxWithin;

    if (mode == 0ULL && need > 0) {
        if (tid == 0) { s_cstar = 0; s_rem = 1; s_wAbove = 0.0; s_res = 0.0; }
        unsigned long long myc = chunkCnt[tid];
        double myw = chunkW[tid];
        sc[tid] = myc; sw[tid] = myw; __syncthreads();
        for (int d = 1; d < 512; d <<= 1) {
            unsigned long long ac = (tid + d < 512) ? sc[tid + d] : 0ULL;
            double aw = (tid + d < 512) ? sw[tid + d] : 0.0;
            __syncthreads();
            sc[tid] += ac; sw[tid] += aw;
            __syncthreads();
        }
        unsigned long long afterC = (tid == 511) ? 0ULL : sc[tid + 1];
        double afterW = (tid == 511) ? 0.0 : sw[tid + 1];
        if (afterC < need && need <= afterC + myc) {
            s_cstar = tid; s_rem = need - afterC; s_wAbove = afterW;
        }
        __syncthreads();
        int cstar = s_cstar;
        unsigned long long rem = s_rem;
        double wAbove = s_wAbove;
        __syncthreads();

        int pb = cstar * CHUNK + 4 * tid;
        unsigned c[4]; double L[4];
        unsigned long long tot = 0; double wtot = 0.0;
        #pragma unroll
        for (int j = 0; j < 4; ++j) {
            c[j] = gH2[pb + j];
            L[j] = (double)__uint_as_float(((unsigned)b1 << H1_SHIFT) | (unsigned)(pb + j));
            tot += c[j];
            wtot += (double)c[j] * L[j];
        }
        sc[tid] = tot; sw[tid] = wtot;
        __syncthreads();
        for (int d = 1; d < 512; d <<= 1) {
            unsigned long long ac = (tid + d < 512) ? sc[tid + d] : 0ULL;
            double aw = (tid + d < 512) ? sw[tid + d] : 0.0;
            __syncthreads();
            sc[tid] += ac; sw[tid] += aw;
            __syncthreads();
        }
        unsigned long long run = (tid == 511) ? 0ULL : sc[tid + 1];
        double wrun = (tid == 511) ? 0.0 : sw[tid + 1];
        #pragma unroll
        for (int j = 3; j >= 0; --j) {
            if (run < rem && rem <= run + c[j]) {
                s_res = wrun + (double)(rem - run) * L[j];
            }
            run += c[j];
            wrun += (double)c[j] * L[j];
        }
        __syncthreads();
        within = wAbove + s_res;
    }

    if (tid == 0) {
        double negLoss = sumAbove + within;
        double result;
        if (posCnt == 0) {
            result = totLoss / (double)n;
        } else {
            result = (posLoss + negLoss) / ((double)posCnt + (double)k + 1e-8);
        }
        out[0] = (float)result;
    }
}

extern "C" void kernel_launch(void* const* d_in, const int* in_sizes, int n_in,
                              void* d_out, int out_size, void* d_ws, size_t ws_size,
                              hipStream_t stream) {
    const float* pred = (const float*)d_in[0];
    const int*   targ = (const int*)d_in[1];
    const float* mask = (const float*)d_in[2];
    int n = in_sizes[0];

    char* ws = (char*)d_ws;
    unsigned long long* ctrl = (unsigned long long*)ws;
    unsigned long long* gcnt = (unsigned long long*)(ws + OFF_CNT);
    unsigned long long* gsum = (unsigned long long*)(ws + OFF_SUM);
    double* p1part = (double*)(ws + OFF_P1);
    unsigned long long* chunkCnt = (unsigned long long*)(ws + OFF_CCNT);
    double* chunkW = (double*)(ws + OFF_CW);
    unsigned* gH2 = (unsigned*)(ws + OFF_H2);

    (void)hipMemsetAsync(ws, 0, MEMSET1, stream);                 // ctrl + gcnt + gsum
    (void)hipMemsetAsync(ws + OFF_H2, 0, H2_BINS * 4, stream);    // H2

    pass1<<<NBLK, NTHR, 0, stream>>>(pred, targ, mask, n, gcnt, gsum, ctrl, p1part);
    findbin<<<1, 1024, 0, stream>>>(gcnt, gsum, ctrl, p1part);
    pass2x<<<NBLK, NTHR, 0, stream>>>(pred, targ, mask, n, ctrl, gH2);
    chunkscan<<<NCHUNK, 256, 0, stream>>>(gH2, ctrl, chunkCnt, chunkW);
    finalize<<<1, 512, 0, stream>>>(gH2, ctrl, chunkCnt, chunkW, (float*)d_out, n);
}